// Round 15
// baseline (75.044 us; speedup 1.0000x reference)
//
#include <hip/hip_runtime.h>
#include <stdint.h>

// DIAGNOSTIC ROUND. Real kernel = R13 fused attn VERBATIM (24.5 us best).
// probe = faithful R13 clone x REP=3 (~75 us) so it outranks the ~40 us
// harness fills in the duration-sorted top-5 and exposes VALUBusy /
// OccupancyPercent / VGPR_Count / WRITE / FETCH for the real structure.
#define TT 1024
#define BB 4
#define REP 3

typedef __fp16 fp16x2 __attribute__((ext_vector_type(2)));
typedef __fp16 fp16x8 __attribute__((ext_vector_type(8)));
typedef float  floatx4 __attribute__((ext_vector_type(4)));
union U32H2 { uint32_t u; fp16x2 h; };
union U4H8  { uint4 u; fp16x8 h; };

__device__ __forceinline__ uint32_t rotl32(uint32_t x, int d) {
  return (x << d) | (x >> (32 - d));
}

// JAX partitionable threefry (key(42)) keep decision  [verified R1]
__device__ __forceinline__ bool keep_at(uint32_t i) {
  uint32_t x0 = 0u, x1 = i;
  const uint32_t ks0 = 0u, ks1 = 42u;
  const uint32_t ks2 = 0x1BD11BDAu ^ ks0 ^ ks1;
  x0 += ks0; x1 += ks1;
#define R4(a,b,c,d)                              \
  x0 += x1; x1 = rotl32(x1,(a)); x1 ^= x0;       \
  x0 += x1; x1 = rotl32(x1,(b)); x1 ^= x0;       \
  x0 += x1; x1 = rotl32(x1,(c)); x1 ^= x0;       \
  x0 += x1; x1 = rotl32(x1,(d)); x1 ^= x0;
  R4(13,15,26,6)   x0 += ks1; x1 += ks2 + 1u;
  R4(17,29,16,24)  x0 += ks2; x1 += ks0 + 2u;
  R4(13,15,26,6)   x0 += ks0; x1 += ks1 + 3u;
  R4(17,29,16,24)  x0 += ks1; x1 += ks2 + 4u;
  R4(13,15,26,6)   x0 += ks2; x1 += ks0 + 5u;
#undef R4
  const uint32_t bits = x0 ^ x1;
  const float u = __uint_as_float((bits >> 9) | 0x3f800000u) - 1.0f;
  return u < 0.8f;
}

__device__ __forceinline__ uint32_t pack2(float x, float y) {
  U32H2 t; t.h = __builtin_amdgcn_cvt_pkrtz(x, y);
  return t.u;
}
__device__ __forceinline__ U4H8 pack8(float4 f0, float4 f1) {
  U4H8 d;
  d.u.x = pack2(f0.x, f0.y); d.u.y = pack2(f0.z, f0.w);
  d.u.z = pack2(f1.x, f1.y); d.u.w = pack2(f1.z, f1.w);
  return d;
}

template <int CTRL>
__device__ __forceinline__ float adddpp(float x) {
  const int s =
      __builtin_amdgcn_update_dpp(0, __float_as_int(x), CTRL, 0xF, 0xF, true);
  return x + __int_as_float(s);
}
__device__ __forceinline__ float radd16(float a) {
  a = adddpp<0xB1>(a);  a = adddpp<0x4E>(a);
  a = adddpp<0x141>(a); a = adddpp<0x140>(a);
  return a;
}

// ---------------- shared body (templated on dest) ----------------
template <bool PROBE>
__device__ __forceinline__ void attn_body(const float* __restrict__ Q,
                                          const float* __restrict__ K,
                                          float* __restrict__ O,
                                          uint32_t ofs) {
  __shared__ float redS[16][8];
  const int tid  = threadIdx.x;
  const int wv   = tid >> 6, ln = tid & 63;
  const int colL = ln & 15;
  const int kgrp = ln >> 4;
  const int g    = blockIdx.x & 63;
  const int b    = blockIdx.x >> 6;

  const float4* Qf = reinterpret_cast<const float4*>(Q) + (size_t)b * TT * 16;
  const float4* Kf = reinterpret_cast<const float4*>(K) + (size_t)b * TT * 16;

  const int arow = g + 64 * (ln & 15);
  const U4H8 qa0 = pack8(Qf[arow * 16 + kgrp * 2],     Qf[arow * 16 + kgrp * 2 + 1]);
  const U4H8 qa1 = pack8(Qf[arow * 16 + 8 + kgrp * 2], Qf[arow * 16 + 8 + kgrp * 2 + 1]);

  int rowD[4]; uint32_t obase[4];
#pragma unroll
  for (int r = 0; r < 4; ++r) {
    rowD[r]  = g + 64 * (kgrp * 4 + r);
    obase[r] = (((uint32_t)b << 20) | ((uint32_t)rowD[r] << 10)) + ofs;
  }

  float p[8][4];
  float sAcc[4] = {0.f, 0.f, 0.f, 0.f};
#pragma unroll
  for (int it = 0; it < 8; ++it) {
    const int jt = it * 8 + wv;
    const int jrow = jt * 16 + colL;
    const U4H8 kb0 = pack8(Kf[jrow * 16 + kgrp * 2],
                           Kf[jrow * 16 + kgrp * 2 + 1]);
    const U4H8 kb1 = pack8(Kf[jrow * 16 + 8 + kgrp * 2],
                           Kf[jrow * 16 + 8 + kgrp * 2 + 1]);
    floatx4 acc = {0.f, 0.f, 0.f, 0.f};
    acc = __builtin_amdgcn_mfma_f32_16x16x32_f16(qa0.h, kb0.h, acc, 0, 0, 0);
    acc = __builtin_amdgcn_mfma_f32_16x16x32_f16(qa1.h, kb1.h, acc, 0, 0, 0);
    const int col = jt * 16 + colL;
#pragma unroll
    for (int r = 0; r < 4; ++r) {
      const float e = (col <= rowD[r]) ? __expf(acc[r] * 0.125f) : 0.f;
      p[it][r] = e;
      sAcc[r] += e;
    }
  }
#pragma unroll
  for (int r = 0; r < 4; ++r) sAcc[r] = radd16(sAcc[r]);
  if (colL == 0) {
#pragma unroll
    for (int r = 0; r < 4; ++r) redS[kgrp * 4 + r][wv] = sAcc[r];
  }
  __syncthreads();
  float rs[4];
#pragma unroll
  for (int r = 0; r < 4; ++r) {
    const int m = kgrp * 4 + r;
    float S = 0.f;
#pragma unroll
    for (int w = 0; w < 8; ++w) S += redS[m][w];
    rs[r] = 1.25f / S;
  }

#pragma unroll
  for (int it = 0; it < 8; ++it) {
    const int jt = it * 8 + wv;
#pragma unroll
    for (int r = 0; r < 4; ++r) {
      const int col = jt * 16 + colL;
      float v = 0.f;
      if (g + 64 * (12 + r) >= jt * 16) {
        const float e = (col <= rowD[r]) ? p[it][r] * rs[r] : 0.f;
        v = keep_at(obase[r] + (uint32_t)col) ? e : 0.f;
      }
      O[obase[r] + (uint32_t)col - (PROBE ? 0 : ofs)] = v;
    }
  }
  if (PROBE) __syncthreads();   // probe reps reuse redS
}

// ---- REAL kernel: R13 verbatim behavior ----
__global__ __launch_bounds__(512)
void attn_kernel(const float* __restrict__ Q, const float* __restrict__ K,
                 float* __restrict__ O) {
  attn_body<false>(Q, K, O, 0u);
}

// ---- PROBE: faithful clone x REP, opaque offset defeats cross-rep CSE ----
__global__ __launch_bounds__(512)
void probe_kernel(const float* __restrict__ Q, const float* __restrict__ K,
                  float* __restrict__ Od) {
  int off = 0;
  for (int rep = 0; rep < REP; ++rep) {
    asm volatile("" : "+s"(off));          // opaque 0: blocks CSE/hoist
    attn_body<true>(Q + off, K + off, Od, (uint32_t)off);
  }
}

extern "C" void kernel_launch(void* const* d_in, const int* in_sizes, int n_in,
                              void* d_out, int out_size, void* d_ws, size_t ws_size,
                              hipStream_t stream) {
  const float* q = (const float*)d_in[0];
  const float* k = (const float*)d_in[1];
  float* out = (float*)d_out;
  if (ws_size >= (size_t)BB * TT * TT * 4 + 4096)   // 16.8 MB dummy store target
    probe_kernel<<<dim3(BB * 64), 512, 0, stream>>>(q, k, (float*)d_ws);
  attn_kernel<<<dim3(BB * 64), 512, 0, stream>>>(q, k, out);
}

// Round 16
// 25.356 us; speedup vs baseline: 2.9596x; 2.9596x over previous
//
#include <hip/hip_runtime.h>
#include <stdint.h>

// B=4, T=1024, D=64 causal attention probs + deterministic JAX dropout.
// Two-kernel split at the natural seam (R15 probe: threefry epilogue ~ half
// the VALU, needs no barrier/tile structure -> give it its own high-occupancy
// kernel). k1: MFMA scores + row sums (R13 frag math verbatim), writes e as
// f16 + per-row 1.25/sum to d_ws. k2: 4096 blocks x 256 thr streaming
// epilogue: block = 1 row, thread = 4 cols, u64 e-read, threefry, dwordx4.
#define TT 1024
#define BB 4

typedef __fp16 fp16x2 __attribute__((ext_vector_type(2)));
typedef __fp16 fp16x8 __attribute__((ext_vector_type(8)));
typedef float  floatx4 __attribute__((ext_vector_type(4)));
union U32H2 { uint32_t u; fp16x2 h; };
union U4H8  { uint4 u; fp16x8 h; };

__device__ __forceinline__ uint32_t rotl32(uint32_t x, int d) {
  return (x << d) | (x >> (32 - d));
}

// JAX partitionable threefry (key(42)) keep decision  [verified R1]
__device__ __forceinline__ bool keep_at(uint32_t i) {
  uint32_t x0 = 0u, x1 = i;
  const uint32_t ks0 = 0u, ks1 = 42u;
  const uint32_t ks2 = 0x1BD11BDAu ^ ks0 ^ ks1;
  x0 += ks0; x1 += ks1;
#define R4(a,b,c,d)                              \
  x0 += x1; x1 = rotl32(x1,(a)); x1 ^= x0;       \
  x0 += x1; x1 = rotl32(x1,(b)); x1 ^= x0;       \
  x0 += x1; x1 = rotl32(x1,(c)); x1 ^= x0;       \
  x0 += x1; x1 = rotl32(x1,(d)); x1 ^= x0;
  R4(13,15,26,6)   x0 += ks1; x1 += ks2 + 1u;
  R4(17,29,16,24)  x0 += ks2; x1 += ks0 + 2u;
  R4(13,15,26,6)   x0 += ks0; x1 += ks1 + 3u;
  R4(17,29,16,24)  x0 += ks1; x1 += ks2 + 4u;
  R4(13,15,26,6)   x0 += ks2; x1 += ks0 + 5u;
#undef R4
  const uint32_t bits = x0 ^ x1;
  const float u = __uint_as_float((bits >> 9) | 0x3f800000u) - 1.0f;
  return u < 0.8f;
}

__device__ __forceinline__ uint32_t pack2(float x, float y) {
  U32H2 t; t.h = __builtin_amdgcn_cvt_pkrtz(x, y);
  return t.u;
}
__device__ __forceinline__ U4H8 pack8(float4 f0, float4 f1) {
  U4H8 d;
  d.u.x = pack2(f0.x, f0.y); d.u.y = pack2(f0.z, f0.w);
  d.u.z = pack2(f1.x, f1.y); d.u.w = pack2(f1.z, f1.w);
  return d;
}

template <int CTRL>
__device__ __forceinline__ float adddpp(float x) {
  const int s =
      __builtin_amdgcn_update_dpp(0, __float_as_int(x), CTRL, 0xF, 0xF, true);
  return x + __int_as_float(s);
}
// sum over the 16 lanes of a (l>>4) group  [verified R11-R15]
__device__ __forceinline__ float radd16(float a) {
  a = adddpp<0xB1>(a);  a = adddpp<0x4E>(a);
  a = adddpp<0x141>(a); a = adddpp<0x140>(a);
  return a;
}

// ---- k1: MFMA scores + row sums; e -> f16 ws, 1.25/sum -> RS ----
__global__ __launch_bounds__(512)
void score_kernel(const float* __restrict__ Q, const float* __restrict__ K,
                  _Float16* __restrict__ E, float* __restrict__ RS) {
  __shared__ float redS[16][8];

  const int tid  = threadIdx.x;
  const int wv   = tid >> 6, ln = tid & 63;
  const int colL = ln & 15;
  const int kgrp = ln >> 4;
  const int g    = blockIdx.x & 63;
  const int b    = blockIdx.x >> 6;

  const float4* Qf = reinterpret_cast<const float4*>(Q) + (size_t)b * TT * 16;
  const float4* Kf = reinterpret_cast<const float4*>(K) + (size_t)b * TT * 16;

  // A-frags (q rows g+64m): lane -> A[row=ln&15][k=kgrp*8+i]  [verified]
  const int arow = g + 64 * (ln & 15);
  const U4H8 qa0 = pack8(Qf[arow * 16 + kgrp * 2],     Qf[arow * 16 + kgrp * 2 + 1]);
  const U4H8 qa1 = pack8(Qf[arow * 16 + 8 + kgrp * 2], Qf[arow * 16 + 8 + kgrp * 2 + 1]);

  int rowD[4]; uint32_t obase[4];
#pragma unroll
  for (int r = 0; r < 4; ++r) {
    rowD[r]  = g + 64 * (kgrp * 4 + r);
    obase[r] = ((uint32_t)b << 20) | ((uint32_t)rowD[r] << 10);
  }

  float sAcc[4] = {0.f, 0.f, 0.f, 0.f};
#pragma unroll
  for (int it = 0; it < 8; ++it) {
    const int jt = it * 8 + wv;
    const int jrow = jt * 16 + colL;
    const U4H8 kb0 = pack8(Kf[jrow * 16 + kgrp * 2],
                           Kf[jrow * 16 + kgrp * 2 + 1]);
    const U4H8 kb1 = pack8(Kf[jrow * 16 + 8 + kgrp * 2],
                           Kf[jrow * 16 + 8 + kgrp * 2 + 1]);
    floatx4 acc = {0.f, 0.f, 0.f, 0.f};
    acc = __builtin_amdgcn_mfma_f32_16x16x32_f16(qa0.h, kb0.h, acc, 0, 0, 0);
    acc = __builtin_amdgcn_mfma_f32_16x16x32_f16(qa1.h, kb1.h, acc, 0, 0, 0);
    const int col = jt * 16 + colL;
#pragma unroll
    for (int r = 0; r < 4; ++r) {
      // no-max softmax: S in [0,8] -> exp safe  [verified R13]
      const float e = (col <= rowD[r]) ? __expf(acc[r] * 0.125f) : 0.f;
      sAcc[r] += e;
      E[obase[r] + (uint32_t)col] = (_Float16)e;
    }
  }
#pragma unroll
  for (int r = 0; r < 4; ++r) sAcc[r] = radd16(sAcc[r]);
  if (colL == 0) {
#pragma unroll
    for (int r = 0; r < 4; ++r) redS[kgrp * 4 + r][wv] = sAcc[r];
  }
  __syncthreads();
  if (wv == 0 && colL == 0) {
#pragma unroll
    for (int r = 0; r < 4; ++r) {
      const int m = kgrp * 4 + r;
      float S = 0.f;
#pragma unroll
      for (int w = 0; w < 8; ++w) S += redS[m][w];
      RS[(b << 10) + g + 64 * m] = 1.25f / S;   // denom + /(1-p) scale
    }
  }
}

// ---- k2: streaming dropout epilogue. Block = one row, thread = 4 cols ----
__global__ __launch_bounds__(256)
void drop_kernel(const _Float16* __restrict__ E, const float* __restrict__ RS,
                 float* __restrict__ O) {
  const int gb  = blockIdx.x;          // b*1024 + row
  const int row = gb & 1023;
  const int tid = threadIdx.x;
  const uint32_t base = (uint32_t)gb << 10;
  const float rs = RS[gb];             // block-uniform -> scalar load
  const int col0 = tid * 4;

  float4 v = {0.f, 0.f, 0.f, 0.f};
  // wave-uniform skip: wave covers cols [256*(tid>>6), +255]
  if ((tid & ~63) * 4 <= row) {
    // load 4 e-values (u64, coalesced)
    const fp16x2* E2 = reinterpret_cast<const fp16x2*>(E + base + col0);
    const fp16x2 e01 = E2[0], e23 = E2[1];
    const uint32_t i0 = base + (uint32_t)col0;
    if (col0 + 0 <= row) v.x = keep_at(i0 + 0) ? (float)e01[0] * rs : 0.f;
    if (col0 + 1 <= row) v.y = keep_at(i0 + 1) ? (float)e01[1] * rs : 0.f;
    if (col0 + 2 <= row) v.z = keep_at(i0 + 2) ? (float)e23[0] * rs : 0.f;
    if (col0 + 3 <= row) v.w = keep_at(i0 + 3) ? (float)e23[1] * rs : 0.f;
  }
  *reinterpret_cast<float4*>(O + base + col0) = v;   // zeros clear the poison
}

extern "C" void kernel_launch(void* const* d_in, const int* in_sizes, int n_in,
                              void* d_out, int out_size, void* d_ws, size_t ws_size,
                              hipStream_t stream) {
  const float* q = (const float*)d_in[0];
  const float* k = (const float*)d_in[1];
  float* out = (float*)d_out;
  _Float16* E = (_Float16*)d_ws;                       // 8.4 MB e-values
  float* RS = (float*)((char*)d_ws + (size_t)BB * TT * TT * 2);  // 16 KB
  score_kernel<<<dim3(BB * 64), 512, 0, stream>>>(q, k, E, RS);
  drop_kernel<<<dim3(BB * TT), 256, 0, stream>>>(E, RS, out);
}